// Round 1
// baseline (553.724 us; speedup 1.0000x reference)
//
#include <hip/hip_runtime.h>
#include <hip/hip_bf16.h>
#include <math.h>

// Problem dims (fixed by reference)
#define B   32
#define P   196      // hw tokens (14x14)
#define C   768
#define NC  4096
#define HH  14

// ---------------------------------------------------------------------------
// K1: SpaceSelfAware + space_fusion (L2 over token axis + GeM over 3x3) +
//     residual add.  One block per (b,c); the 196-token channel vector lives
//     in LDS.  Neighbor windows are same-channel shifts with zero padding
//     (pad top=2, bottom=0, left=1, right=1).
// out: pre[b, p, c] = pooled + patch   (row-major b,p,c)
// ---------------------------------------------------------------------------
__global__ __launch_bounds__(256) void k_ssa(const float* __restrict__ t,
                                             float* __restrict__ pre) {
    const int bc = blockIdx.x;        // b*C + c
    const int b = bc / C, c = bc % C;
    __shared__ float x[P];
    __shared__ float partial[9][4];
    __shared__ float inv_norm[9];
    const int tid = threadIdx.x;

    if (tid < P) x[tid] = t[((size_t)b * P + tid) * C + c];
    __syncthreads();

    float v[9];
    const int p = tid;
    if (p < P) {
        const int i = p / HH, j = p % HH;
        const float xp = x[p];
#pragma unroll
        for (int k = 0; k < 9; ++k) {
            const int ki = k / 3, kj = k % 3;
            const int i2 = i + ki - 2;   // pad top = 2
            const int j2 = j + kj - 1;   // pad left = 1
            const float nb = (i2 >= 0 && i2 < HH && j2 >= 0 && j2 < HH)
                                 ? x[i2 * HH + j2] : 0.0f;
            v[k] = xp * nb;
        }
    } else {
#pragma unroll
        for (int k = 0; k < 9; ++k) v[k] = 0.0f;
    }

    // deterministic reduction: 64-lane butterfly then 4 partials in fixed order
    const int lane = tid & 63, wid = tid >> 6;
#pragma unroll
    for (int k = 0; k < 9; ++k) {
        float r = v[k] * v[k];
#pragma unroll
        for (int off = 32; off > 0; off >>= 1) r += __shfl_xor(r, off);
        if (lane == 0) partial[k][wid] = r;
    }
    __syncthreads();
    if (tid < 9) {
        const float s = partial[tid][0] + partial[tid][1] +
                        partial[tid][2] + partial[tid][3];
        inv_norm[tid] = 1.0f / fmaxf(sqrtf(s), 1e-12f);
    }
    __syncthreads();

    if (p < P) {
        float acc = 0.0f;
#pragma unroll
        for (int k = 0; k < 9; ++k) {
            const float u = fmaxf(v[k] * inv_norm[k], 1e-6f);
            acc += u * u * u;
        }
        const float pooled = cbrtf(acc * (1.0f / 9.0f));
        pre[((size_t)b * P + p) * C + c] = pooled + x[p];
    }
}

// ---------------------------------------------------------------------------
// K2: L2 normalize each (b,p) row over the 768 channels.
// ---------------------------------------------------------------------------
__global__ __launch_bounds__(256) void k_rownorm(const float* __restrict__ in,
                                                 float* __restrict__ out) {
    const int row = blockIdx.x;               // b*P + p
    const float* r = in + (size_t)row * C;
    const int tid = threadIdx.x;
    float vals[3];
    float s = 0.0f;
#pragma unroll
    for (int q = 0; q < 3; ++q) {
        vals[q] = r[tid + q * 256];
        s += vals[q] * vals[q];
    }
    __shared__ float partial[4];
    __shared__ float inv;
#pragma unroll
    for (int off = 32; off > 0; off >>= 1) s += __shfl_xor(s, off);
    if ((tid & 63) == 0) partial[tid >> 6] = s;
    __syncthreads();
    if (tid == 0)
        inv = 1.0f / fmaxf(sqrtf(partial[0] + partial[1] + partial[2] + partial[3]), 1e-12f);
    __syncthreads();
    float* o = out + (size_t)row * C;
#pragma unroll
    for (int q = 0; q < 3; ++q) o[tid + q * 256] = vals[q] * inv;
}

// ---------------------------------------------------------------------------
// K3/K4: f32 GEMM  C = act(A @ B + bias).  A:(M,K) B:(K,N) row-major.
// 64x64 tile, BK=16, 256 threads, 4x4 micro-tile per thread.
// ---------------------------------------------------------------------------
template <bool GELU>
__global__ __launch_bounds__(256) void k_gemm(const float* __restrict__ A,
                                              const float* __restrict__ Bm,
                                              const float* __restrict__ bias,
                                              float* __restrict__ Cm,
                                              int M, int N, int K) {
    constexpr int BK = 16;
    __shared__ float As[BK][68];   // As[k][m], padded stride (16B aligned rows)
    __shared__ float Bs[BK][68];   // Bs[k][n]

    const int tid = threadIdx.x;
    const int tx = tid % 16, ty = tid / 16;
    const int bm = blockIdx.y * 64, bn = blockIdx.x * 64;

    const int arow = tid / 4, acol = (tid % 4) * 4;   // A tile load coords
    const int brow = tid / 16, bcol = (tid % 16) * 4; // B tile load coords

    float acc[4][4] = {};

    for (int kt = 0; kt < K; kt += BK) {
        const float4 av = *(const float4*)&A[(size_t)(bm + arow) * K + kt + acol];
        const float4 bv = *(const float4*)&Bm[(size_t)(kt + brow) * N + bn + bcol];
        __syncthreads();
        As[acol + 0][arow] = av.x;
        As[acol + 1][arow] = av.y;
        As[acol + 2][arow] = av.z;
        As[acol + 3][arow] = av.w;
        *(float4*)&Bs[brow][bcol] = bv;
        __syncthreads();
#pragma unroll
        for (int kk = 0; kk < BK; ++kk) {
            const float4 a4 = *(const float4*)&As[kk][ty * 4];
            const float4 b4 = *(const float4*)&Bs[kk][tx * 4];
            const float a[4] = {a4.x, a4.y, a4.z, a4.w};
            const float bb[4] = {b4.x, b4.y, b4.z, b4.w};
#pragma unroll
            for (int i = 0; i < 4; ++i)
#pragma unroll
                for (int j = 0; j < 4; ++j) acc[i][j] += a[i] * bb[j];
        }
    }

#pragma unroll
    for (int i = 0; i < 4; ++i) {
        const int m = bm + ty * 4 + i;
        float o[4];
#pragma unroll
        for (int j = 0; j < 4; ++j) {
            float val = acc[i][j] + bias[bn + tx * 4 + j];
            if (GELU) val = 0.5f * val * (1.0f + erff(val * 0.70710678118654752f));
            o[j] = val;
        }
        *(float4*)&Cm[(size_t)m * N + bn + tx * 4] = *(float4*)o;
    }
}

// ---------------------------------------------------------------------------
// K5: GeM over tokens: g[b,c] = (mean_p clip(x,1e-6)^3)^(1/3)
// ---------------------------------------------------------------------------
__global__ __launch_bounds__(256) void k_gempool(const float* __restrict__ tk,
                                                 float* __restrict__ g) {
    const int b = blockIdx.x;
    const int tid = threadIdx.x;
    for (int c = tid; c < C; c += 256) {
        float s = 0.0f;
        for (int p = 0; p < P; ++p) {
            const float v = fmaxf(tk[((size_t)b * P + p) * C + c], 1e-6f);
            s += v * v * v;
        }
        g[b * C + c] = cbrtf(s * (1.0f / (float)P));
    }
}

// ---------------------------------------------------------------------------
// K6: head GEMM (32x768)@(768x4096) + bias -> out (pre-normalize)
// one thread per output column n; 32 accumulators (all batches).
// ---------------------------------------------------------------------------
__global__ __launch_bounds__(256) void k_head(const float* __restrict__ g,
                                              const float* __restrict__ W,
                                              const float* __restrict__ hb,
                                              float* __restrict__ out) {
    const int n = blockIdx.x * 256 + threadIdx.x;   // 16 blocks
    __shared__ float gs[32][64];
    float acc[32];
#pragma unroll
    for (int b = 0; b < 32; ++b) acc[b] = 0.0f;

    for (int k0 = 0; k0 < C; k0 += 64) {
        const int t = threadIdx.x;
#pragma unroll
        for (int q = 0; q < 8; ++q) {
            const int idx = t + q * 256;
            gs[idx >> 6][idx & 63] = g[(idx >> 6) * C + k0 + (idx & 63)];
        }
        __syncthreads();
        for (int kk = 0; kk < 64; ++kk) {
            const float w = W[(size_t)(k0 + kk) * NC + n];
#pragma unroll
            for (int b = 0; b < 32; ++b) acc[b] += gs[b][kk] * w;
        }
        __syncthreads();
    }
    const float hbn = hb[n];
#pragma unroll
    for (int b = 0; b < 32; ++b) out[(size_t)b * NC + n] = acc[b] + hbn;
}

// ---------------------------------------------------------------------------
// K7: L2-normalize each batch row of out (4096) in place.
// ---------------------------------------------------------------------------
__global__ __launch_bounds__(256) void k_outnorm(float* __restrict__ out) {
    const int b = blockIdx.x;
    float* r = out + (size_t)b * NC;
    const int tid = threadIdx.x;
    float v[16];
    float s = 0.0f;
#pragma unroll
    for (int q = 0; q < 16; ++q) {
        v[q] = r[tid + q * 256];
        s += v[q] * v[q];
    }
    __shared__ float partial[4];
    __shared__ float inv;
#pragma unroll
    for (int off = 32; off > 0; off >>= 1) s += __shfl_xor(s, off);
    if ((tid & 63) == 0) partial[tid >> 6] = s;
    __syncthreads();
    if (tid == 0)
        inv = 1.0f / fmaxf(sqrtf(partial[0] + partial[1] + partial[2] + partial[3]), 1e-12f);
    __syncthreads();
#pragma unroll
    for (int q = 0; q < 16; ++q) r[tid + q * 256] = v[q] * inv;
}

// ---------------------------------------------------------------------------
extern "C" void kernel_launch(void* const* d_in, const int* in_sizes, int n_in,
                              void* d_out, int out_size, void* d_ws, size_t ws_size,
                              hipStream_t stream) {
    const float* patch  = (const float*)d_in[0];
    const float* fc1_w  = (const float*)d_in[1];
    const float* fc1_b  = (const float*)d_in[2];
    const float* fc2_w  = (const float*)d_in[3];
    const float* fc2_b  = (const float*)d_in[4];
    const float* head_w = (const float*)d_in[5];
    const float* head_b = (const float*)d_in[6];
    float* out = (float*)d_out;

    const size_t big = (size_t)B * P * C;    // 4,816,896 elements
    float* bufA = (float*)d_ws;              // pre / hdn
    float* bufB = bufA + big;                // tokensN / tokens2
    float* gbuf = bufB + big;                // (32,768)

    // K1: SSA + fusion + residual -> bufA
    k_ssa<<<dim3(B * C), dim3(256), 0, stream>>>(patch, bufA);
    // K2: channel L2 norm -> bufB
    k_rownorm<<<dim3(B * P), dim3(256), 0, stream>>>(bufA, bufB);
    // K3: fc1 + gelu -> bufA
    k_gemm<true><<<dim3(C / 64, (B * P) / 64), dim3(256), 0, stream>>>(
        bufB, fc1_w, fc1_b, bufA, B * P, C, C);
    // K4: fc2 -> bufB
    k_gemm<false><<<dim3(C / 64, (B * P) / 64), dim3(256), 0, stream>>>(
        bufA, fc2_w, fc2_b, bufB, B * P, C, C);
    // K5: GeM over tokens -> gbuf
    k_gempool<<<dim3(B), dim3(256), 0, stream>>>(bufB, gbuf);
    // K6: head GEMM -> out (pre-normalized)
    k_head<<<dim3(NC / 256), dim3(256), 0, stream>>>(gbuf, head_w, head_b, out);
    // K7: normalize rows of out
    k_outnorm<<<dim3(B), dim3(256), 0, stream>>>(out);
}

// Round 2
// 362.130 us; speedup vs baseline: 1.5291x; 1.5291x over previous
//
#include <hip/hip_runtime.h>
#include <hip/hip_bf16.h>
#include <math.h>

// Problem dims (fixed by reference)
#define B   32
#define P   196      // hw tokens (14x14)
#define C   768
#define NC  4096
#define HH  14

// ---------------------------------------------------------------------------
// K1: SpaceSelfAware + space_fusion (L2 over token axis + GeM over 3x3) +
//     residual add.  One block per (b,c); the 196-token channel vector lives
//     in LDS.  Neighbor windows are same-channel shifts with zero padding
//     (pad top=2, bottom=0, left=1, right=1).
// out: pre[b, p, c] = pooled + patch   (row-major b,p,c)
// ---------------------------------------------------------------------------
__global__ __launch_bounds__(256) void k_ssa(const float* __restrict__ t,
                                             float* __restrict__ pre) {
    const int bc = blockIdx.x;        // b*C + c
    const int b = bc / C, c = bc % C;
    __shared__ float x[P];
    __shared__ float partial[9][4];
    __shared__ float inv_norm[9];
    const int tid = threadIdx.x;

    if (tid < P) x[tid] = t[((size_t)b * P + tid) * C + c];
    __syncthreads();

    float v[9];
    const int p = tid;
    if (p < P) {
        const int i = p / HH, j = p % HH;
        const float xp = x[p];
#pragma unroll
        for (int k = 0; k < 9; ++k) {
            const int ki = k / 3, kj = k % 3;
            const int i2 = i + ki - 2;   // pad top = 2
            const int j2 = j + kj - 1;   // pad left = 1
            const float nb = (i2 >= 0 && i2 < HH && j2 >= 0 && j2 < HH)
                                 ? x[i2 * HH + j2] : 0.0f;
            v[k] = xp * nb;
        }
    } else {
#pragma unroll
        for (int k = 0; k < 9; ++k) v[k] = 0.0f;
    }

    // deterministic reduction: 64-lane butterfly then 4 partials in fixed order
    const int lane = tid & 63, wid = tid >> 6;
#pragma unroll
    for (int k = 0; k < 9; ++k) {
        float r = v[k] * v[k];
#pragma unroll
        for (int off = 32; off > 0; off >>= 1) r += __shfl_xor(r, off);
        if (lane == 0) partial[k][wid] = r;
    }
    __syncthreads();
    if (tid < 9) {
        const float s = partial[tid][0] + partial[tid][1] +
                        partial[tid][2] + partial[tid][3];
        inv_norm[tid] = 1.0f / fmaxf(sqrtf(s), 1e-12f);
    }
    __syncthreads();

    if (p < P) {
        float acc = 0.0f;
#pragma unroll
        for (int k = 0; k < 9; ++k) {
            const float u = fmaxf(v[k] * inv_norm[k], 1e-6f);
            acc += u * u * u;
        }
        const float pooled = cbrtf(acc * (1.0f / 9.0f));
        pre[((size_t)b * P + p) * C + c] = pooled + x[p];
    }
}

// ---------------------------------------------------------------------------
// K2: L2 normalize each (b,p) row over the 768 channels.
// ---------------------------------------------------------------------------
__global__ __launch_bounds__(256) void k_rownorm(const float* __restrict__ in,
                                                 float* __restrict__ out) {
    const int row = blockIdx.x;               // b*P + p
    const float* r = in + (size_t)row * C;
    const int tid = threadIdx.x;
    float vals[3];
    float s = 0.0f;
#pragma unroll
    for (int q = 0; q < 3; ++q) {
        vals[q] = r[tid + q * 256];
        s += vals[q] * vals[q];
    }
    __shared__ float partial[4];
    __shared__ float inv;
#pragma unroll
    for (int off = 32; off > 0; off >>= 1) s += __shfl_xor(s, off);
    if ((tid & 63) == 0) partial[tid >> 6] = s;
    __syncthreads();
    if (tid == 0)
        inv = 1.0f / fmaxf(sqrtf(partial[0] + partial[1] + partial[2] + partial[3]), 1e-12f);
    __syncthreads();
    float* o = out + (size_t)row * C;
#pragma unroll
    for (int q = 0; q < 3; ++q) o[tid + q * 256] = vals[q] * inv;
}

// ---------------------------------------------------------------------------
// K3/K4: f32 GEMM  C = act(A @ B + bias).  A:(M,K) B:(K,N) row-major.
// 64x64 tile, BK=16, 256 threads, 4x4 micro-tile per thread.
// ---------------------------------------------------------------------------
template <bool GELU>
__global__ __launch_bounds__(256) void k_gemm(const float* __restrict__ A,
                                              const float* __restrict__ Bm,
                                              const float* __restrict__ bias,
                                              float* __restrict__ Cm,
                                              int M, int N, int K) {
    constexpr int BK = 16;
    __shared__ float As[BK][68];   // As[k][m], padded stride (16B aligned rows)
    __shared__ float Bs[BK][68];   // Bs[k][n]

    const int tid = threadIdx.x;
    const int tx = tid % 16, ty = tid / 16;
    const int bm = blockIdx.y * 64, bn = blockIdx.x * 64;

    const int arow = tid / 4, acol = (tid % 4) * 4;   // A tile load coords
    const int brow = tid / 16, bcol = (tid % 16) * 4; // B tile load coords

    float acc[4][4] = {};

    for (int kt = 0; kt < K; kt += BK) {
        const float4 av = *(const float4*)&A[(size_t)(bm + arow) * K + kt + acol];
        const float4 bv = *(const float4*)&Bm[(size_t)(kt + brow) * N + bn + bcol];
        __syncthreads();
        As[acol + 0][arow] = av.x;
        As[acol + 1][arow] = av.y;
        As[acol + 2][arow] = av.z;
        As[acol + 3][arow] = av.w;
        *(float4*)&Bs[brow][bcol] = bv;
        __syncthreads();
#pragma unroll
        for (int kk = 0; kk < BK; ++kk) {
            const float4 a4 = *(const float4*)&As[kk][ty * 4];
            const float4 b4 = *(const float4*)&Bs[kk][tx * 4];
            const float a[4] = {a4.x, a4.y, a4.z, a4.w};
            const float bb[4] = {b4.x, b4.y, b4.z, b4.w};
#pragma unroll
            for (int i = 0; i < 4; ++i)
#pragma unroll
                for (int j = 0; j < 4; ++j) acc[i][j] += a[i] * bb[j];
        }
    }

#pragma unroll
    for (int i = 0; i < 4; ++i) {
        const int m = bm + ty * 4 + i;
        float o[4];
#pragma unroll
        for (int j = 0; j < 4; ++j) {
            float val = acc[i][j] + bias[bn + tx * 4 + j];
            if (GELU) val = 0.5f * val * (1.0f + erff(val * 0.70710678118654752f));
            o[j] = val;
        }
        *(float4*)&Cm[(size_t)m * N + bn + tx * 4] = *(float4*)o;
    }
}

// ---------------------------------------------------------------------------
// K5: GeM over tokens: g[b,c] = (mean_p clip(x,1e-6)^3)^(1/3)
// grid (B*3) blocks: block handles one 256-channel tile of one batch.
// ---------------------------------------------------------------------------
__global__ __launch_bounds__(256) void k_gempool(const float* __restrict__ tk,
                                                 float* __restrict__ g) {
    const int b = blockIdx.x / 3;
    const int c = (blockIdx.x % 3) * 256 + threadIdx.x;
    float s = 0.0f;
#pragma unroll 4
    for (int p = 0; p < P; ++p) {
        const float v = fmaxf(tk[((size_t)b * P + p) * C + c], 1e-6f);
        s += v * v * v;
    }
    g[b * C + c] = cbrtf(s * (1.0f / (float)P));
}

// ---------------------------------------------------------------------------
// K6: head GEMM (32x768)@(768x4096) + bias -> out (pre-normalize)
// grid (8 n-tiles, 32 batches) = 256 blocks. Each block: batch b's g-row in
// LDS (3 KB), streams a 512-column W slice with float2 loads.
// blockIdx.x fastest -> the 32 blocks sharing a W slice land on one XCD,
// so each 1.5 MB slice is HBM-read once and L2-served 31 times.
// ---------------------------------------------------------------------------
__global__ __launch_bounds__(256) void k_head(const float* __restrict__ g,
                                              const float* __restrict__ W,
                                              const float* __restrict__ hb,
                                              float* __restrict__ out) {
    const int b = blockIdx.y;
    const int n = blockIdx.x * 512 + threadIdx.x * 2;
    __shared__ float gs[C];
    for (int q = threadIdx.x; q < C; q += 256) gs[q] = g[b * C + q];
    __syncthreads();

    float ax = 0.0f, ay = 0.0f;
#pragma unroll 8
    for (int k = 0; k < C; ++k) {
        const float2 w = *(const float2*)&W[(size_t)k * NC + n];
        ax += gs[k] * w.x;
        ay += gs[k] * w.y;
    }
    float2 o = {ax + hb[n], ay + hb[n + 1]};
    *(float2*)&out[(size_t)b * NC + n] = o;
}

// ---------------------------------------------------------------------------
// K7: L2-normalize each batch row of out (4096) in place.
// ---------------------------------------------------------------------------
__global__ __launch_bounds__(256) void k_outnorm(float* __restrict__ out) {
    const int b = blockIdx.x;
    float* r = out + (size_t)b * NC;
    const int tid = threadIdx.x;
    float v[16];
    float s = 0.0f;
#pragma unroll
    for (int q = 0; q < 16; ++q) {
        v[q] = r[tid + q * 256];
        s += v[q] * v[q];
    }
    __shared__ float partial[4];
    __shared__ float inv;
#pragma unroll
    for (int off = 32; off > 0; off >>= 1) s += __shfl_xor(s, off);
    if ((tid & 63) == 0) partial[tid >> 6] = s;
    __syncthreads();
    if (tid == 0)
        inv = 1.0f / fmaxf(sqrtf(partial[0] + partial[1] + partial[2] + partial[3]), 1e-12f);
    __syncthreads();
#pragma unroll
    for (int q = 0; q < 16; ++q) r[tid + q * 256] = v[q] * inv;
}

// ---------------------------------------------------------------------------
extern "C" void kernel_launch(void* const* d_in, const int* in_sizes, int n_in,
                              void* d_out, int out_size, void* d_ws, size_t ws_size,
                              hipStream_t stream) {
    const float* patch  = (const float*)d_in[0];
    const float* fc1_w  = (const float*)d_in[1];
    const float* fc1_b  = (const float*)d_in[2];
    const float* fc2_w  = (const float*)d_in[3];
    const float* fc2_b  = (const float*)d_in[4];
    const float* head_w = (const float*)d_in[5];
    const float* head_b = (const float*)d_in[6];
    float* out = (float*)d_out;

    const size_t big = (size_t)B * P * C;    // 4,816,896 elements
    float* bufA = (float*)d_ws;              // pre / hdn
    float* bufB = bufA + big;                // tokensN / tokens2
    float* gbuf = bufB + big;                // (32,768)

    // K1: SSA + fusion + residual -> bufA
    k_ssa<<<dim3(B * C), dim3(256), 0, stream>>>(patch, bufA);
    // K2: channel L2 norm -> bufB
    k_rownorm<<<dim3(B * P), dim3(256), 0, stream>>>(bufA, bufB);
    // K3: fc1 + gelu -> bufA
    k_gemm<true><<<dim3(C / 64, (B * P) / 64), dim3(256), 0, stream>>>(
        bufB, fc1_w, fc1_b, bufA, B * P, C, C);
    // K4: fc2 -> bufB
    k_gemm<false><<<dim3(C / 64, (B * P) / 64), dim3(256), 0, stream>>>(
        bufA, fc2_w, fc2_b, bufB, B * P, C, C);
    // K5: GeM over tokens -> gbuf
    k_gempool<<<dim3(B * 3), dim3(256), 0, stream>>>(bufB, gbuf);
    // K6: head GEMM -> out (pre-normalized)
    k_head<<<dim3(NC / 512, B), dim3(256), 0, stream>>>(gbuf, head_w, head_b, out);
    // K7: normalize rows of out
    k_outnorm<<<dim3(B), dim3(256), 0, stream>>>(out);
}

// Round 3
// 206.333 us; speedup vs baseline: 2.6836x; 1.7551x over previous
//
#include <hip/hip_runtime.h>
#include <hip/hip_bf16.h>
#include <math.h>

// Problem dims (fixed by reference)
#define B   32
#define P   196      // hw tokens (14x14)
#define C   768
#define NC  4096
#define HH  14

typedef _Float16 half8 __attribute__((ext_vector_type(8)));
typedef _Float16 half4 __attribute__((ext_vector_type(4)));
typedef float f32x4 __attribute__((ext_vector_type(4)));

#define GLOAD_LDS16(g, l)                                                      \
    __builtin_amdgcn_global_load_lds(                                          \
        (const __attribute__((address_space(1))) void*)(g),                    \
        (__attribute__((address_space(3))) void*)(l), 16, 0, 0)

// ---------------------------------------------------------------------------
// K1: SpaceSelfAware + space_fusion (L2 over token axis + GeM over 3x3) +
//     residual add.  One block per (b,c); the 196-token channel vector in LDS.
// ---------------------------------------------------------------------------
__global__ __launch_bounds__(256) void k_ssa(const float* __restrict__ t,
                                             float* __restrict__ pre) {
    const int bc = blockIdx.x;        // b*C + c
    const int b = bc / C, c = bc % C;
    __shared__ float x[P];
    __shared__ float partial[9][4];
    __shared__ float inv_norm[9];
    const int tid = threadIdx.x;

    if (tid < P) x[tid] = t[((size_t)b * P + tid) * C + c];
    __syncthreads();

    float v[9];
    const int p = tid;
    if (p < P) {
        const int i = p / HH, j = p % HH;
        const float xp = x[p];
#pragma unroll
        for (int k = 0; k < 9; ++k) {
            const int ki = k / 3, kj = k % 3;
            const int i2 = i + ki - 2;   // pad top = 2
            const int j2 = j + kj - 1;   // pad left = 1
            const float nb = (i2 >= 0 && i2 < HH && j2 >= 0 && j2 < HH)
                                 ? x[i2 * HH + j2] : 0.0f;
            v[k] = xp * nb;
        }
    } else {
#pragma unroll
        for (int k = 0; k < 9; ++k) v[k] = 0.0f;
    }

    const int lane = tid & 63, wid = tid >> 6;
#pragma unroll
    for (int k = 0; k < 9; ++k) {
        float r = v[k] * v[k];
#pragma unroll
        for (int off = 32; off > 0; off >>= 1) r += __shfl_xor(r, off);
        if (lane == 0) partial[k][wid] = r;
    }
    __syncthreads();
    if (tid < 9) {
        const float s = partial[tid][0] + partial[tid][1] +
                        partial[tid][2] + partial[tid][3];
        inv_norm[tid] = 1.0f / fmaxf(sqrtf(s), 1e-12f);
    }
    __syncthreads();

    if (p < P) {
        float acc = 0.0f;
#pragma unroll
        for (int k = 0; k < 9; ++k) {
            const float u = fmaxf(v[k] * inv_norm[k], 1e-6f);
            acc += u * u * u;
        }
        const float pooled = cbrtf(acc * (1.0f / 9.0f));
        pre[((size_t)b * P + p) * C + c] = pooled + x[p];
    }
}

// ---------------------------------------------------------------------------
// K2: L2 normalize each (b,p) row over 768 channels; write f16 tokens.
// ---------------------------------------------------------------------------
__global__ __launch_bounds__(256) void k_rownorm(const float* __restrict__ in,
                                                 _Float16* __restrict__ out) {
    const int row = blockIdx.x;               // b*P + p
    const float* r = in + (size_t)row * C;
    const int tid = threadIdx.x;
    float vals[3];
    float s = 0.0f;
#pragma unroll
    for (int q = 0; q < 3; ++q) {
        vals[q] = r[tid + q * 256];
        s += vals[q] * vals[q];
    }
    __shared__ float partial[4];
    __shared__ float inv;
#pragma unroll
    for (int off = 32; off > 0; off >>= 1) s += __shfl_xor(s, off);
    if ((tid & 63) == 0) partial[tid >> 6] = s;
    __syncthreads();
    if (tid == 0)
        inv = 1.0f / fmaxf(sqrtf(partial[0] + partial[1] + partial[2] + partial[3]), 1e-12f);
    __syncthreads();
    _Float16* o = out + (size_t)row * C;
#pragma unroll
    for (int q = 0; q < 3; ++q) o[tid + q * 256] = (_Float16)(vals[q] * inv);
}

// ---------------------------------------------------------------------------
// K2b: weight transpose + f32->f16:  W (K x N) -> Wt (N x K)
// ---------------------------------------------------------------------------
__global__ __launch_bounds__(256) void k_wt(const float* __restrict__ W,
                                            _Float16* __restrict__ Wt) {
    __shared__ float t[32][33];
    const int k0 = blockIdx.x * 32, n0 = blockIdx.y * 32;
    const int r = threadIdx.x / 32, c = threadIdx.x % 32;
#pragma unroll
    for (int q = 0; q < 4; ++q)
        t[r + q * 8][c] = W[(size_t)(k0 + r + q * 8) * C + n0 + c];
    __syncthreads();
#pragma unroll
    for (int q = 0; q < 4; ++q)
        Wt[(size_t)(n0 + r + q * 8) * C + k0 + c] = (_Float16)t[c][r + q * 8];
}

// ---------------------------------------------------------------------------
// K3/K4: f16 MFMA GEMM.  Tok: (M x K) f16 row-major (B-operand).
// Wt: (N x K) f16 row-major (A-operand).  Out = act(Tok @ W + bias).
// 128x128 tile, BK=32, 4 waves (each 64n x 64m as 4x4 16x16x32 fragments).
// LDS layout [kb][row][8]: conflict-free ds_read_b128; staged by
// global_load_lds(16B) with per-lane global addresses (wave w owns kb=w).
// mfma(A=weight frag, B=token frag): D row=n, col=m -> lane holds 4
// consecutive n => contiguous epilogue stores.
// ---------------------------------------------------------------------------
template <bool GELU>
__global__ __launch_bounds__(256) void k_mfma_gemm(
    const _Float16* __restrict__ Tok,   // (M, K=768)
    const _Float16* __restrict__ Wt,    // (N=768, K=768)
    const float* __restrict__ bias,     // (N)
    void* __restrict__ Cout) {          // f16 (GELU) or f32
    __shared__ _Float16 lA[4][128][8];  // weights  [kb][n][k']
    __shared__ _Float16 lB[4][128][8];  // tokens   [kb][m][k']
    const int tid = threadIdx.x;
    const int w = tid >> 6, l = tid & 63;
    const int l15 = l & 15, lk = l >> 4;
    const int m0 = blockIdx.x * 128, n0 = blockIdx.y * 128;
    const int wm = (w & 1) * 64, wn = (w >> 1) * 64;

    f32x4 acc[4][4] = {};   // [fa over n][fb over m]

    const _Float16* gA0 = Wt + (size_t)(n0 + l) * C + w * 8;
    const _Float16* gA1 = Wt + (size_t)(n0 + 64 + l) * C + w * 8;
    const _Float16* gB0 = Tok + (size_t)((size_t)blockIdx.x * 128 + l) * C + w * 8;
    const _Float16* gB1 = gB0 + (size_t)64 * C;

    for (int kt = 0; kt < C; kt += 32) {
        __syncthreads();                 // previous tile consumed
        GLOAD_LDS16(gA0 + kt, &lA[w][0][0]);
        GLOAD_LDS16(gA1 + kt, &lA[w][64][0]);
        GLOAD_LDS16(gB0 + kt, &lB[w][0][0]);
        GLOAD_LDS16(gB1 + kt, &lB[w][64][0]);
        __syncthreads();                 // drains vmcnt -> tile ready

        half8 af[4];
#pragma unroll
        for (int fa = 0; fa < 4; ++fa)
            af[fa] = *(const half8*)&lA[lk][wn + fa * 16 + l15][0];
#pragma unroll
        for (int fb = 0; fb < 4; ++fb) {
            const half8 bf = *(const half8*)&lB[lk][wm + fb * 16 + l15][0];
#pragma unroll
            for (int fa = 0; fa < 4; ++fa)
                acc[fa][fb] = __builtin_amdgcn_mfma_f32_16x16x32_f16(
                    af[fa], bf, acc[fa][fb], 0, 0, 0);
        }
    }

    // epilogue: lane holds D[n = nb + r][m], r=0..3 consecutive n
#pragma unroll
    for (int fa = 0; fa < 4; ++fa) {
        const int nb = n0 + wn + fa * 16 + lk * 4;
        const float4 bv = *(const float4*)&bias[nb];
#pragma unroll
        for (int fb = 0; fb < 4; ++fb) {
            const int m = m0 + wm + fb * 16 + l15;
            if (GELU) {
                half4 o;
#pragma unroll
                for (int r = 0; r < 4; ++r) {
                    float v = acc[fa][fb][r] + ((const float*)&bv)[r];
                    v = 0.5f * v * (1.0f + erff(v * 0.70710678118654752f));
                    o[r] = (_Float16)v;
                }
                *(half4*)&((_Float16*)Cout)[(size_t)m * C + nb] = o;
            } else {
                float4 o;
#pragma unroll
                for (int r = 0; r < 4; ++r)
                    ((float*)&o)[r] = acc[fa][fb][r] + ((const float*)&bv)[r];
                *(float4*)&((float*)Cout)[(size_t)m * C + nb] = o;
            }
        }
    }
}

// ---------------------------------------------------------------------------
// K5: GeM over tokens: g[b,c] = (mean_p clip(x,1e-6)^3)^(1/3)
// ---------------------------------------------------------------------------
__global__ __launch_bounds__(256) void k_gempool(const float* __restrict__ tk,
                                                 float* __restrict__ g) {
    const int b = blockIdx.x / 3;
    const int c = (blockIdx.x % 3) * 256 + threadIdx.x;
    float s = 0.0f;
#pragma unroll 4
    for (int p = 0; p < P; ++p) {
        const float v = fmaxf(tk[((size_t)b * P + p) * C + c], 1e-6f);
        s += v * v * v;
    }
    g[b * C + c] = cbrtf(s * (1.0f / (float)P));
}

// ---------------------------------------------------------------------------
// K6: head GEMM (32x768)@(768x4096) + bias -> out.  grid (8 n-tiles, 32 b).
// ---------------------------------------------------------------------------
__global__ __launch_bounds__(256) void k_head(const float* __restrict__ g,
                                              const float* __restrict__ W,
                                              const float* __restrict__ hb,
                                              float* __restrict__ out) {
    const int b = blockIdx.y;
    const int n = blockIdx.x * 512 + threadIdx.x * 2;
    __shared__ float gs[C];
    for (int q = threadIdx.x; q < C; q += 256) gs[q] = g[b * C + q];
    __syncthreads();

    float ax = 0.0f, ay = 0.0f;
#pragma unroll 8
    for (int k = 0; k < C; ++k) {
        const float2 w = *(const float2*)&W[(size_t)k * NC + n];
        ax += gs[k] * w.x;
        ay += gs[k] * w.y;
    }
    float2 o = {ax + hb[n], ay + hb[n + 1]};
    *(float2*)&out[(size_t)b * NC + n] = o;
}

// ---------------------------------------------------------------------------
// K7: L2-normalize each batch row of out (4096) in place.
// ---------------------------------------------------------------------------
__global__ __launch_bounds__(256) void k_outnorm(float* __restrict__ out) {
    const int b = blockIdx.x;
    float* r = out + (size_t)b * NC;
    const int tid = threadIdx.x;
    float v[16];
    float s = 0.0f;
#pragma unroll
    for (int q = 0; q < 16; ++q) {
        v[q] = r[tid + q * 256];
        s += v[q] * v[q];
    }
    __shared__ float partial[4];
    __shared__ float inv;
#pragma unroll
    for (int off = 32; off > 0; off >>= 1) s += __shfl_xor(s, off);
    if ((tid & 63) == 0) partial[tid >> 6] = s;
    __syncthreads();
    if (tid == 0)
        inv = 1.0f / fmaxf(sqrtf(partial[0] + partial[1] + partial[2] + partial[3]), 1e-12f);
    __syncthreads();
#pragma unroll
    for (int q = 0; q < 16; ++q) r[tid + q * 256] = v[q] * inv;
}

// ---------------------------------------------------------------------------
extern "C" void kernel_launch(void* const* d_in, const int* in_sizes, int n_in,
                              void* d_out, int out_size, void* d_ws, size_t ws_size,
                              hipStream_t stream) {
    const float* patch  = (const float*)d_in[0];
    const float* fc1_w  = (const float*)d_in[1];
    const float* fc1_b  = (const float*)d_in[2];
    const float* fc2_w  = (const float*)d_in[3];
    const float* fc2_b  = (const float*)d_in[4];
    const float* head_w = (const float*)d_in[5];
    const float* head_b = (const float*)d_in[6];
    float* out = (float*)d_out;

    const size_t big = (size_t)B * P * C;        // 4,816,896 elements
    float*    pre  = (float*)d_ws;               // [big] f32; later reused as tok2
    _Float16* tokN = (_Float16*)(pre + big);     // [big] f16
    _Float16* hdn  = tokN + big;                 // [big] f16
    _Float16* wt1  = hdn + big;                  // [768*768] f16
    _Float16* wt2  = wt1 + C * C;                // [768*768] f16
    float*    gbuf = (float*)(wt2 + C * C);      // [32*768] f32
    float*    tok2 = pre;                        // reuse

    // K1: SSA + fusion + residual -> pre
    k_ssa<<<dim3(B * C), dim3(256), 0, stream>>>(patch, pre);
    // weight transposes (independent)
    k_wt<<<dim3(C / 32, C / 32), dim3(256), 0, stream>>>(fc1_w, wt1);
    k_wt<<<dim3(C / 32, C / 32), dim3(256), 0, stream>>>(fc2_w, wt2);
    // K2: channel L2 norm -> tokN (f16)
    k_rownorm<<<dim3(B * P), dim3(256), 0, stream>>>(pre, tokN);
    // K3: fc1 + gelu -> hdn (f16)
    k_mfma_gemm<true><<<dim3((B * P) / 128, C / 128), dim3(256), 0, stream>>>(
        tokN, wt1, fc1_b, hdn);
    // K4: fc2 -> tok2 (f32)
    k_mfma_gemm<false><<<dim3((B * P) / 128, C / 128), dim3(256), 0, stream>>>(
        hdn, wt2, fc2_b, tok2);
    // K5: GeM over tokens -> gbuf
    k_gempool<<<dim3(B * 3), dim3(256), 0, stream>>>(tok2, gbuf);
    // K6: head GEMM -> out (pre-normalized)
    k_head<<<dim3(NC / 512, B), dim3(256), 0, stream>>>(gbuf, head_w, head_b, out);
    // K7: normalize rows of out
    k_outnorm<<<dim3(B), dim3(256), 0, stream>>>(out);
}

// Round 4
// 189.331 us; speedup vs baseline: 2.9246x; 1.0898x over previous
//
#include <hip/hip_runtime.h>
#include <hip/hip_bf16.h>
#include <math.h>

// Problem dims (fixed by reference)
#define B   32
#define P   196      // hw tokens (14x14)
#define C   768
#define NC  4096
#define HH  14

typedef _Float16 half8 __attribute__((ext_vector_type(8)));
typedef _Float16 half4 __attribute__((ext_vector_type(4)));
typedef float f32x4 __attribute__((ext_vector_type(4)));

#define GLOAD_LDS16(g, l)                                                      \
    __builtin_amdgcn_global_load_lds(                                          \
        (const __attribute__((address_space(1))) void*)(g),                    \
        (__attribute__((address_space(3))) void*)(l), 16, 0, 0)

// ---------------------------------------------------------------------------
// K1: SpaceSelfAware + space_fusion + residual.
// Block = (64-channel tile, batch).  x tile (196 x 64 f32, 49 KB) in LDS,
// coalesced float4 loads/stores.  Thread (cc = tid&63, g = tid>>6) owns
// channel cc, tokens [g*49, g*49+49).  All wave lanes share p -> uniform
// branches, consecutive cc -> conflict-free LDS (2 lanes/bank).
// ---------------------------------------------------------------------------
__global__ __launch_bounds__(256) void k_ssa(const float* __restrict__ t,
                                             float* __restrict__ pre) {
    const int b = blockIdx.y, c0 = blockIdx.x * 64;
    __shared__ float x[P * 64];           // [p][cc]
    __shared__ float part[4][9][64];
    __shared__ float inv_norm[9][64];
    const int tid = threadIdx.x;
    const int cc = tid & 63, g = tid >> 6;

    // coalesced tile load: 3136 float4
    for (int it = 0; it < 13; ++it) {
        const int idx = it * 256 + tid;
        if (idx < (P * 64) / 4) {
            const int f = idx * 4;
            const int p = f >> 6, c = f & 63;
            *(float4*)&x[f] =
                *(const float4*)&t[((size_t)b * P + p) * C + c0 + c];
        }
    }
    __syncthreads();

    const int p0 = g * 49;
    // pass 1: squared sums over this thread's tokens, per window slot k
    float s[9] = {};
    for (int p = p0; p < p0 + 49; ++p) {
        const int i = p / HH, j = p % HH;
        const float xp = x[p * 64 + cc];
        const float xp2 = xp * xp;
#pragma unroll
        for (int k = 0; k < 9; ++k) {
            const int i2 = i + k / 3 - 2;   // pad top = 2
            const int j2 = j + k % 3 - 1;   // pad left = 1
            if (i2 >= 0 && i2 < HH && j2 >= 0 && j2 < HH) {
                const float nb = x[(i2 * HH + j2) * 64 + cc];
                s[k] += xp2 * nb * nb;
            }
        }
    }
#pragma unroll
    for (int k = 0; k < 9; ++k) part[g][k][cc] = s[k];
    __syncthreads();
    for (int k = g; k < 9; k += 4) {
        const float t4 = part[0][k][cc] + part[1][k][cc] +
                         part[2][k][cc] + part[3][k][cc];
        inv_norm[k][cc] = 1.0f / fmaxf(sqrtf(t4), 1e-12f);
    }
    __syncthreads();

    float invn[9];
#pragma unroll
    for (int k = 0; k < 9; ++k) invn[k] = inv_norm[k][cc];

    // pass 2: recompute products, GeM over the 3x3 window, residual, store
    for (int p = p0; p < p0 + 49; ++p) {
        const int i = p / HH, j = p % HH;
        const float xp = x[p * 64 + cc];
        float acc = 0.0f;
#pragma unroll
        for (int k = 0; k < 9; ++k) {
            const int i2 = i + k / 3 - 2;
            const int j2 = j + k % 3 - 1;
            float v = 0.0f;
            if (i2 >= 0 && i2 < HH && j2 >= 0 && j2 < HH)
                v = xp * x[(i2 * HH + j2) * 64 + cc];
            const float u = fmaxf(v * invn[k], 1e-6f);
            acc += u * u * u;
        }
        const float pooled = cbrtf(acc * (1.0f / 9.0f));
        pre[((size_t)b * P + p) * C + c0 + cc] = pooled + xp;
    }
}

// ---------------------------------------------------------------------------
// K2: L2 normalize each (b,p) row over 768 channels; write f16 tokens.
// ---------------------------------------------------------------------------
__global__ __launch_bounds__(256) void k_rownorm(const float* __restrict__ in,
                                                 _Float16* __restrict__ out) {
    const int row = blockIdx.x;               // b*P + p
    const float* r = in + (size_t)row * C;
    const int tid = threadIdx.x;
    float vals[3];
    float s = 0.0f;
#pragma unroll
    for (int q = 0; q < 3; ++q) {
        vals[q] = r[tid + q * 256];
        s += vals[q] * vals[q];
    }
    __shared__ float partial[4];
    __shared__ float inv;
#pragma unroll
    for (int off = 32; off > 0; off >>= 1) s += __shfl_xor(s, off);
    if ((tid & 63) == 0) partial[tid >> 6] = s;
    __syncthreads();
    if (tid == 0)
        inv = 1.0f / fmaxf(sqrtf(partial[0] + partial[1] + partial[2] + partial[3]), 1e-12f);
    __syncthreads();
    _Float16* o = out + (size_t)row * C;
#pragma unroll
    for (int q = 0; q < 3; ++q) o[tid + q * 256] = (_Float16)(vals[q] * inv);
}

// ---------------------------------------------------------------------------
// K2b: weight transpose + f32->f16:  W (K x N) -> Wt (N x K)
// ---------------------------------------------------------------------------
__global__ __launch_bounds__(256) void k_wt(const float* __restrict__ W,
                                            _Float16* __restrict__ Wt) {
    __shared__ float t[32][33];
    const int k0 = blockIdx.x * 32, n0 = blockIdx.y * 32;
    const int r = threadIdx.x / 32, c = threadIdx.x % 32;
#pragma unroll
    for (int q = 0; q < 4; ++q)
        t[r + q * 8][c] = W[(size_t)(k0 + r + q * 8) * C + n0 + c];
    __syncthreads();
#pragma unroll
    for (int q = 0; q < 4; ++q)
        Wt[(size_t)(n0 + r + q * 8) * C + k0 + c] = (_Float16)t[c][r + q * 8];
}

// ---------------------------------------------------------------------------
// K3/K4: f16 MFMA GEMM.  Tok: (M x K) f16 row-major (B-operand).
// Wt: (N x K) f16 row-major (A-operand).  Out = act(Tok @ W + bias).
// 128x128 tile, BK=32, 4 waves.
// ---------------------------------------------------------------------------
template <bool GELU>
__global__ __launch_bounds__(256) void k_mfma_gemm(
    const _Float16* __restrict__ Tok,   // (M, K=768)
    const _Float16* __restrict__ Wt,    // (N=768, K=768)
    const float* __restrict__ bias,     // (N)
    void* __restrict__ Cout) {          // f16 (GELU) or f32
    __shared__ _Float16 lA[4][128][8];  // weights  [kb][n][k']
    __shared__ _Float16 lB[4][128][8];  // tokens   [kb][m][k']
    const int tid = threadIdx.x;
    const int w = tid >> 6, l = tid & 63;
    const int l15 = l & 15, lk = l >> 4;
    const int m0 = blockIdx.x * 128, n0 = blockIdx.y * 128;
    const int wm = (w & 1) * 64, wn = (w >> 1) * 64;

    f32x4 acc[4][4] = {};   // [fa over n][fb over m]

    const _Float16* gA0 = Wt + (size_t)(n0 + l) * C + w * 8;
    const _Float16* gA1 = Wt + (size_t)(n0 + 64 + l) * C + w * 8;
    const _Float16* gB0 = Tok + (size_t)((size_t)blockIdx.x * 128 + l) * C + w * 8;
    const _Float16* gB1 = gB0 + (size_t)64 * C;

    for (int kt = 0; kt < C; kt += 32) {
        __syncthreads();                 // previous tile consumed
        GLOAD_LDS16(gA0 + kt, &lA[w][0][0]);
        GLOAD_LDS16(gA1 + kt, &lA[w][64][0]);
        GLOAD_LDS16(gB0 + kt, &lB[w][0][0]);
        GLOAD_LDS16(gB1 + kt, &lB[w][64][0]);
        __syncthreads();                 // drains vmcnt -> tile ready

        half8 af[4];
#pragma unroll
        for (int fa = 0; fa < 4; ++fa)
            af[fa] = *(const half8*)&lA[lk][wn + fa * 16 + l15][0];
#pragma unroll
        for (int fb = 0; fb < 4; ++fb) {
            const half8 bf = *(const half8*)&lB[lk][wm + fb * 16 + l15][0];
#pragma unroll
            for (int fa = 0; fa < 4; ++fa)
                acc[fa][fb] = __builtin_amdgcn_mfma_f32_16x16x32_f16(
                    af[fa], bf, acc[fa][fb], 0, 0, 0);
        }
    }

    // epilogue: lane holds D[n = nb + r][m], r=0..3 consecutive n
#pragma unroll
    for (int fa = 0; fa < 4; ++fa) {
        const int nb = n0 + wn + fa * 16 + lk * 4;
        const float4 bv = *(const float4*)&bias[nb];
#pragma unroll
        for (int fb = 0; fb < 4; ++fb) {
            const int m = m0 + wm + fb * 16 + l15;
            if (GELU) {
                half4 o;
#pragma unroll
                for (int r = 0; r < 4; ++r) {
                    float v = acc[fa][fb][r] + ((const float*)&bv)[r];
                    v = 0.5f * v * (1.0f + erff(v * 0.70710678118654752f));
                    o[r] = (_Float16)v;
                }
                *(half4*)&((_Float16*)Cout)[(size_t)m * C + nb] = o;
            } else {
                float4 o;
#pragma unroll
                for (int r = 0; r < 4; ++r)
                    ((float*)&o)[r] = acc[fa][fb][r] + ((const float*)&bv)[r];
                *(float4*)&((float*)Cout)[(size_t)m * C + nb] = o;
            }
        }
    }
}

// ---------------------------------------------------------------------------
// K5: GeM over tokens: g[b,c] = (mean_p clip(x,1e-6)^3)^(1/3)
// ---------------------------------------------------------------------------
__global__ __launch_bounds__(256) void k_gempool(const float* __restrict__ tk,
                                                 float* __restrict__ g) {
    const int b = blockIdx.x / 3;
    const int c = (blockIdx.x % 3) * 256 + threadIdx.x;
    float s = 0.0f;
#pragma unroll 4
    for (int p = 0; p < P; ++p) {
        const float v = fmaxf(tk[((size_t)b * P + p) * C + c], 1e-6f);
        s += v * v * v;
    }
    g[b * C + c] = cbrtf(s * (1.0f / (float)P));
}

// ---------------------------------------------------------------------------
// K6: head GEMM (32x768)@(768x4096) + bias -> out.  grid (8 n-tiles, 32 b).
// ---------------------------------------------------------------------------
__global__ __launch_bounds__(256) void k_head(const float* __restrict__ g,
                                              const float* __restrict__ W,
                                              const float* __restrict__ hb,
                                              float* __restrict__ out) {
    const int b = blockIdx.y;
    const int n = blockIdx.x * 512 + threadIdx.x * 2;
    __shared__ float gs[C];
    for (int q = threadIdx.x; q < C; q += 256) gs[q] = g[b * C + q];
    __syncthreads();

    float ax = 0.0f, ay = 0.0f;
#pragma unroll 8
    for (int k = 0; k < C; ++k) {
        const float2 w = *(const float2*)&W[(size_t)k * NC + n];
        ax += gs[k] * w.x;
        ay += gs[k] * w.y;
    }
    float2 o = {ax + hb[n], ay + hb[n + 1]};
    *(float2*)&out[(size_t)b * NC + n] = o;
}

// ---------------------------------------------------------------------------
// K7: L2-normalize each batch row of out (4096) in place.
// ---------------------------------------------------------------------------
__global__ __launch_bounds__(256) void k_outnorm(float* __restrict__ out) {
    const int b = blockIdx.x;
    float* r = out + (size_t)b * NC;
    const int tid = threadIdx.x;
    float v[16];
    float s = 0.0f;
#pragma unroll
    for (int q = 0; q < 16; ++q) {
        v[q] = r[tid + q * 256];
        s += v[q] * v[q];
    }
    __shared__ float partial[4];
    __shared__ float inv;
#pragma unroll
    for (int off = 32; off > 0; off >>= 1) s += __shfl_xor(s, off);
    if ((tid & 63) == 0) partial[tid >> 6] = s;
    __syncthreads();
    if (tid == 0)
        inv = 1.0f / fmaxf(sqrtf(partial[0] + partial[1] + partial[2] + partial[3]), 1e-12f);
    __syncthreads();
#pragma unroll
    for (int q = 0; q < 16; ++q) r[tid + q * 256] = v[q] * inv;
}

// ---------------------------------------------------------------------------
extern "C" void kernel_launch(void* const* d_in, const int* in_sizes, int n_in,
                              void* d_out, int out_size, void* d_ws, size_t ws_size,
                              hipStream_t stream) {
    const float* patch  = (const float*)d_in[0];
    const float* fc1_w  = (const float*)d_in[1];
    const float* fc1_b  = (const float*)d_in[2];
    const float* fc2_w  = (const float*)d_in[3];
    const float* fc2_b  = (const float*)d_in[4];
    const float* head_w = (const float*)d_in[5];
    const float* head_b = (const float*)d_in[6];
    float* out = (float*)d_out;

    const size_t big = (size_t)B * P * C;        // 4,816,896 elements
    float*    pre  = (float*)d_ws;               // [big] f32; later reused as tok2
    _Float16* tokN = (_Float16*)(pre + big);     // [big] f16
    _Float16* hdn  = tokN + big;                 // [big] f16
    _Float16* wt1  = hdn + big;                  // [768*768] f16
    _Float16* wt2  = wt1 + C * C;                // [768*768] f16
    float*    gbuf = (float*)(wt2 + C * C);      // [32*768] f32
    float*    tok2 = pre;                        // reuse

    // K1: SSA + fusion + residual -> pre
    k_ssa<<<dim3(C / 64, B), dim3(256), 0, stream>>>(patch, pre);
    // weight transposes (independent)
    k_wt<<<dim3(C / 32, C / 32), dim3(256), 0, stream>>>(fc1_w, wt1);
    k_wt<<<dim3(C / 32, C / 32), dim3(256), 0, stream>>>(fc2_w, wt2);
    // K2: channel L2 norm -> tokN (f16)
    k_rownorm<<<dim3(B * P), dim3(256), 0, stream>>>(pre, tokN);
    // K3: fc1 + gelu -> hdn (f16)
    k_mfma_gemm<true><<<dim3((B * P) / 128, C / 128), dim3(256), 0, stream>>>(
        tokN, wt1, fc1_b, hdn);
    // K4: fc2 -> tok2 (f32)
    k_mfma_gemm<false><<<dim3((B * P) / 128, C / 128), dim3(256), 0, stream>>>(
        hdn, wt2, fc2_b, tok2);
    // K5: GeM over tokens -> gbuf
    k_gempool<<<dim3(B * 3), dim3(256), 0, stream>>>(tok2, gbuf);
    // K6: head GEMM -> out (pre-normalized)
    k_head<<<dim3(NC / 512, B), dim3(256), 0, stream>>>(gbuf, head_w, head_b, out);
    // K7: normalize rows of out
    k_outnorm<<<dim3(B), dim3(256), 0, stream>>>(out);
}

// Round 5
// 155.223 us; speedup vs baseline: 3.5673x; 1.2197x over previous
//
#include <hip/hip_runtime.h>
#include <hip/hip_bf16.h>
#include <math.h>

// Problem dims (fixed by reference)
#define B   32
#define P   196      // hw tokens (14x14)
#define C   768
#define NC  4096
#define HH  14

typedef _Float16 half8 __attribute__((ext_vector_type(8)));
typedef _Float16 half4 __attribute__((ext_vector_type(4)));
typedef float f32x4 __attribute__((ext_vector_type(4)));

#define GLOAD_LDS16(g, l)                                                      \
    __builtin_amdgcn_global_load_lds(                                          \
        (const __attribute__((address_space(1))) void*)(g),                    \
        (__attribute__((address_space(3))) void*)(l), 16, 0, 0)

// ---------------------------------------------------------------------------
// K1: SpaceSelfAware + space_fusion + residual.
// Block = (32-channel tile, batch), grid 24 x 32 = 768 blocks (3/CU).
// x staged in LDS as a ZERO-PADDED spatial halo tile [16+... 16 rows][16 cols]
// x 32 ch (32 KB): rows -2..13 -> 0..15 (pad top=2, bottom=0 fits row 15
// unused), cols -1..14 -> 0..15.  All 9 window taps become branchless
// constant-offset LDS reads.  Thread (cc=tid&31, g=tid>>5) owns channel cc,
// tokens p = g, g+8, ...  (i,j maintained incrementally - no div/mod).
// ---------------------------------------------------------------------------
__global__ __launch_bounds__(256) void k_ssa(const float* __restrict__ t,
                                             float* __restrict__ pre) {
    const int b = blockIdx.y, c0 = blockIdx.x * 32;
    __shared__ float xp_[256 * 32];        // [(i+2)*16 + (j+1)][cc]
    __shared__ float part[8][9][32];
    __shared__ float inv_norm[9][32];
    const int tid = threadIdx.x;
    const int cc = tid & 31, g = tid >> 5;

    // zero entire padded tile (halo included)
#pragma unroll
    for (int q = 0; q < 32; ++q) xp_[q * 256 + tid] = 0.0f;
    __syncthreads();

    // coalesced fill of the valid region: 1568 float4
    for (int idx = tid; idx < (P * 32) / 4; idx += 256) {
        const int f = idx * 4;
        const int p = f >> 5, c = f & 31;
        const int i = p / HH, j = p % HH;
        *(float4*)&xp_[((i + 2) * 16 + (j + 1)) * 32 + c] =
            *(const float4*)&t[((size_t)b * P + p) * C + c0 + c];
    }
    __syncthreads();

    // pass 1: per-slot squared sums over this thread's tokens
    float s[9] = {};
    {
        int i = 0, j = g;
        for (int p = g; p < P; p += 8) {
            const int base = ((i + 2) * 16 + (j + 1)) * 32 + cc;
            const float xp = xp_[base];
            const float xp2 = xp * xp;
#pragma unroll
            for (int k = 0; k < 9; ++k) {
                const int off = ((k / 3) - 2) * 16 + (k % 3) - 1;  // const
                const float nb = xp_[base + off * 32];
                s[k] += xp2 * nb * nb;
            }
            j += 8;
            if (j >= HH) { j -= HH; ++i; }
        }
    }
#pragma unroll
    for (int k = 0; k < 9; ++k) part[g][k][cc] = s[k];
    __syncthreads();
    for (int k = g; k < 9; k += 8) {
        float t4 = 0.0f;
#pragma unroll
        for (int q = 0; q < 8; ++q) t4 += part[q][k][cc];
        inv_norm[k][cc] = 1.0f / fmaxf(sqrtf(t4), 1e-12f);
    }
    __syncthreads();

    float invn[9];
#pragma unroll
    for (int k = 0; k < 9; ++k) invn[k] = inv_norm[k][cc];

    // pass 2: window products, GeM over 3x3, residual, coalesced store
    {
        int i = 0, j = g;
        for (int p = g; p < P; p += 8) {
            const int base = ((i + 2) * 16 + (j + 1)) * 32 + cc;
            const float xp = xp_[base];
            float acc = 0.0f;
#pragma unroll
            for (int k = 0; k < 9; ++k) {
                const int off = ((k / 3) - 2) * 16 + (k % 3) - 1;
                const float v = xp * xp_[base + off * 32];
                const float u = fmaxf(v * invn[k], 1e-6f);
                acc += u * u * u;
            }
            pre[((size_t)b * P + p) * C + c0 + cc] =
                cbrtf(acc * (1.0f / 9.0f)) + xp;
            j += 8;
            if (j >= HH) { j -= HH; ++i; }
        }
    }
}

// ---------------------------------------------------------------------------
// K2: L2 normalize each (b,p) row over 768 channels; write f16 tokens.
// ---------------------------------------------------------------------------
__global__ __launch_bounds__(256) void k_rownorm(const float* __restrict__ in,
                                                 _Float16* __restrict__ out) {
    const int row = blockIdx.x;               // b*P + p
    const float* r = in + (size_t)row * C;
    const int tid = threadIdx.x;
    float vals[3];
    float s = 0.0f;
#pragma unroll
    for (int q = 0; q < 3; ++q) {
        vals[q] = r[tid + q * 256];
        s += vals[q] * vals[q];
    }
    __shared__ float partial[4];
    __shared__ float inv;
#pragma unroll
    for (int off = 32; off > 0; off >>= 1) s += __shfl_xor(s, off);
    if ((tid & 63) == 0) partial[tid >> 6] = s;
    __syncthreads();
    if (tid == 0)
        inv = 1.0f / fmaxf(sqrtf(partial[0] + partial[1] + partial[2] + partial[3]), 1e-12f);
    __syncthreads();
    _Float16* o = out + (size_t)row * C;
#pragma unroll
    for (int q = 0; q < 3; ++q) o[tid + q * 256] = (_Float16)(vals[q] * inv);
}

// ---------------------------------------------------------------------------
// K2b: weight transpose + f32->f16:  W (K x N) -> Wt (N x K)
// ---------------------------------------------------------------------------
__global__ __launch_bounds__(256) void k_wt(const float* __restrict__ W,
                                            _Float16* __restrict__ Wt) {
    __shared__ float t[32][33];
    const int k0 = blockIdx.x * 32, n0 = blockIdx.y * 32;
    const int r = threadIdx.x / 32, c = threadIdx.x % 32;
#pragma unroll
    for (int q = 0; q < 4; ++q)
        t[r + q * 8][c] = W[(size_t)(k0 + r + q * 8) * C + n0 + c];
    __syncthreads();
#pragma unroll
    for (int q = 0; q < 4; ++q)
        Wt[(size_t)(n0 + r + q * 8) * C + k0 + c] = (_Float16)t[c][r + q * 8];
}

// ---------------------------------------------------------------------------
// K3/K4: f16 MFMA GEMM, 2-phase double-buffered (issue STAGE(t+1) BEFORE
// compute(t); one drain+barrier per tile -> HBM latency hides under MFMA).
// Tile 64M x 128N, BK=32, 4 waves (wave: 64n x 32m = 4x2 frags), grid 98x6
// = 588 blocks (~2.3/CU).  LDS 2 x 12 KB.
// Tok (M,K) f16 = B-operand; Wt (N,K) f16 = A-operand.
// ---------------------------------------------------------------------------
template <bool GELU>
__global__ __launch_bounds__(256) void k_mfma_gemm(
    const _Float16* __restrict__ Tok,   // (M=6272, K=768)
    const _Float16* __restrict__ Wt,    // (N=768,  K=768)
    const float* __restrict__ bias,     // (N)
    void* __restrict__ Cout) {          // f16 (GELU) or f32
    __shared__ _Float16 lA[2][4][128][8];  // [buf][kb][n][k']
    __shared__ _Float16 lB[2][4][64][8];   // [buf][kb][m][k']
    const int tid = threadIdx.x;
    const int w = tid >> 6, l = tid & 63;
    const int l15 = l & 15, lk = l >> 4;
    const int m0 = blockIdx.x * 64, n0 = blockIdx.y * 128;
    const int wn = (w & 1) * 64, wm = (w >> 1) * 32;

    f32x4 acc[4][2] = {};   // [fa over n][fb over m]

    const _Float16* gA0 = Wt + (size_t)(n0 + l) * C + w * 8;
    const _Float16* gA1 = Wt + (size_t)(n0 + 64 + l) * C + w * 8;
    const _Float16* gB0 = Tok + (size_t)(m0 + l) * C + w * 8;

    // prologue: stage tile 0 into buf 0
    GLOAD_LDS16(gA0, &lA[0][w][0][0]);
    GLOAD_LDS16(gA1, &lA[0][w][64][0]);
    GLOAD_LDS16(gB0, &lB[0][w][0][0]);
    __syncthreads();

    int cur = 0;
    for (int t = 0; t < 24; ++t) {
        if (t < 23) {                      // issue next tile FIRST
            const int kt = (t + 1) * 32;
            GLOAD_LDS16(gA0 + kt, &lA[cur ^ 1][w][0][0]);
            GLOAD_LDS16(gA1 + kt, &lA[cur ^ 1][w][64][0]);
            GLOAD_LDS16(gB0 + kt, &lB[cur ^ 1][w][0][0]);
        }
        half8 af[4], bf[2];
#pragma unroll
        for (int fa = 0; fa < 4; ++fa)
            af[fa] = *(const half8*)&lA[cur][lk][wn + fa * 16 + l15][0];
#pragma unroll
        for (int fb = 0; fb < 2; ++fb)
            bf[fb] = *(const half8*)&lB[cur][lk][wm + fb * 16 + l15][0];
#pragma unroll
        for (int fa = 0; fa < 4; ++fa)
#pragma unroll
            for (int fb = 0; fb < 2; ++fb)
                acc[fa][fb] = __builtin_amdgcn_mfma_f32_16x16x32_f16(
                    af[fa], bf[fb], acc[fa][fb], 0, 0, 0);
        __syncthreads();                   // drains next-tile loads (issued
        cur ^= 1;                          // before compute -> latency hidden)
    }

    // epilogue: lane holds D[n = nb + r][m], r=0..3 consecutive n
#pragma unroll
    for (int fa = 0; fa < 4; ++fa) {
        const int nb = n0 + wn + fa * 16 + lk * 4;
        const float4 bv = *(const float4*)&bias[nb];
#pragma unroll
        for (int fb = 0; fb < 2; ++fb) {
            const int m = m0 + wm + fb * 16 + l15;
            if (GELU) {
                half4 o;
#pragma unroll
                for (int r = 0; r < 4; ++r) {
                    float v = acc[fa][fb][r] + ((const float*)&bv)[r];
                    v = 0.5f * v * (1.0f + erff(v * 0.70710678118654752f));
                    o[r] = (_Float16)v;
                }
                *(half4*)&((_Float16*)Cout)[(size_t)m * C + nb] = o;
            } else {
                float4 o;
#pragma unroll
                for (int r = 0; r < 4; ++r)
                    ((float*)&o)[r] = acc[fa][fb][r] + ((const float*)&bv)[r];
                *(float4*)&((float*)Cout)[(size_t)m * C + nb] = o;
            }
        }
    }
}

// ---------------------------------------------------------------------------
// K5: GeM over tokens: g[b,c] = (mean_p clip(x,1e-6)^3)^(1/3)
// ---------------------------------------------------------------------------
__global__ __launch_bounds__(256) void k_gempool(const float* __restrict__ tk,
                                                 float* __restrict__ g) {
    const int b = blockIdx.x / 3;
    const int c = (blockIdx.x % 3) * 256 + threadIdx.x;
    float s = 0.0f;
#pragma unroll 4
    for (int p = 0; p < P; ++p) {
        const float v = fmaxf(tk[((size_t)b * P + p) * C + c], 1e-6f);
        s += v * v * v;
    }
    g[b * C + c] = cbrtf(s * (1.0f / (float)P));
}

// ---------------------------------------------------------------------------
// K6: head GEMM (32x768)@(768x4096) + bias -> out.  grid (8 n-tiles, 32 b).
// ---------------------------------------------------------------------------
__global__ __launch_bounds__(256) void k_head(const float* __restrict__ g,
                                              const float* __restrict__ W,
                                              const float* __restrict__ hb,
                                              float* __restrict__ out) {
    const int b = blockIdx.y;
    const int n = blockIdx.x * 512 + threadIdx.x * 2;
    __shared__ float gs[C];
    for (int q = threadIdx.x; q < C; q += 256) gs[q] = g[b * C + q];
    __syncthreads();

    float ax = 0.0f, ay = 0.0f;
#pragma unroll 8
    for (int k = 0; k < C; ++k) {
        const float2 w = *(const float2*)&W[(size_t)k * NC + n];
        ax += gs[k] * w.x;
        ay += gs[k] * w.y;
    }
    float2 o = {ax + hb[n], ay + hb[n + 1]};
    *(float2*)&out[(size_t)b * NC + n] = o;
}

// ---------------------------------------------------------------------------
// K7: L2-normalize each batch row of out (4096) in place.
// ---------------------------------------------------------------------------
__global__ __launch_bounds__(256) void k_outnorm(float* __restrict__ out) {
    const int b = blockIdx.x;
    float* r = out + (size_t)b * NC;
    const int tid = threadIdx.x;
    float v[16];
    float s = 0.0f;
#pragma unroll
    for (int q = 0; q < 16; ++q) {
        v[q] = r[tid + q * 256];
        s += v[q] * v[q];
    }
    __shared__ float partial[4];
    __shared__ float inv;
#pragma unroll
    for (int off = 32; off > 0; off >>= 1) s += __shfl_xor(s, off);
    if ((tid & 63) == 0) partial[tid >> 6] = s;
    __syncthreads();
    if (tid == 0)
        inv = 1.0f / fmaxf(sqrtf(partial[0] + partial[1] + partial[2] + partial[3]), 1e-12f);
    __syncthreads();
#pragma unroll
    for (int q = 0; q < 16; ++q) r[tid + q * 256] = v[q] * inv;
}

// ---------------------------------------------------------------------------
extern "C" void kernel_launch(void* const* d_in, const int* in_sizes, int n_in,
                              void* d_out, int out_size, void* d_ws, size_t ws_size,
                              hipStream_t stream) {
    const float* patch  = (const float*)d_in[0];
    const float* fc1_w  = (const float*)d_in[1];
    const float* fc1_b  = (const float*)d_in[2];
    const float* fc2_w  = (const float*)d_in[3];
    const float* fc2_b  = (const float*)d_in[4];
    const float* head_w = (const float*)d_in[5];
    const float* head_b = (const float*)d_in[6];
    float* out = (float*)d_out;

    const size_t big = (size_t)B * P * C;        // 4,816,896 elements
    float*    pre  = (float*)d_ws;               // [big] f32; later reused as tok2
    _Float16* tokN = (_Float16*)(pre + big);     // [big] f16
    _Float16* hdn  = tokN + big;                 // [big] f16
    _Float16* wt1  = hdn + big;                  // [768*768] f16
    _Float16* wt2  = wt1 + C * C;                // [768*768] f16
    float*    gbuf = (float*)(wt2 + C * C);      // [32*768] f32
    float*    tok2 = pre;                        // reuse

    // K1: SSA + fusion + residual -> pre
    k_ssa<<<dim3(C / 32, B), dim3(256), 0, stream>>>(patch, pre);
    // weight transposes (independent)
    k_wt<<<dim3(C / 32, C / 32), dim3(256), 0, stream>>>(fc1_w, wt1);
    k_wt<<<dim3(C / 32, C / 32), dim3(256), 0, stream>>>(fc2_w, wt2);
    // K2: channel L2 norm -> tokN (f16)
    k_rownorm<<<dim3(B * P), dim3(256), 0, stream>>>(pre, tokN);
    // K3: fc1 + gelu -> hdn (f16)
    k_mfma_gemm<true><<<dim3((B * P) / 64, C / 128), dim3(256), 0, stream>>>(
        tokN, wt1, fc1_b, hdn);
    // K4: fc2 -> tok2 (f32)
    k_mfma_gemm<false><<<dim3((B * P) / 64, C / 128), dim3(256), 0, stream>>>(
        hdn, wt2, fc2_b, tok2);
    // K5: GeM over tokens -> gbuf
    k_gempool<<<dim3(B * 3), dim3(256), 0, stream>>>(tok2, gbuf);
    // K6: head GEMM -> out (pre-normalized)
    k_head<<<dim3(NC / 512, B), dim3(256), 0, stream>>>(gbuf, head_w, head_b, out);
    // K7: normalize rows of out
    k_outnorm<<<dim3(B), dim3(256), 0, stream>>>(out);
}

// Round 6
// 132.170 us; speedup vs baseline: 4.1895x; 1.1744x over previous
//
#include <hip/hip_runtime.h>
#include <hip/hip_bf16.h>
#include <math.h>

// Problem dims (fixed by reference)
#define B   32
#define P   196      // hw tokens (14x14)
#define C   768
#define NC  4096
#define HH  14
#define KSPLIT 24    // 768 / 32

typedef _Float16 half8 __attribute__((ext_vector_type(8)));
typedef _Float16 half4 __attribute__((ext_vector_type(4)));
typedef float f32x4 __attribute__((ext_vector_type(4)));

#define GLOAD_LDS16(g, l)                                                      \
    __builtin_amdgcn_global_load_lds(                                          \
        (const __attribute__((address_space(1))) void*)(g),                    \
        (__attribute__((address_space(3))) void*)(l), 16, 0, 0)

// ---------------------------------------------------------------------------
// K1: SpaceSelfAware + space_fusion + residual.
// Block = (32-channel tile, batch).  Zero-padded spatial halo tile in LDS;
// branchless 9-tap window; incremental (i,j).
// ---------------------------------------------------------------------------
__global__ __launch_bounds__(256) void k_ssa(const float* __restrict__ t,
                                             float* __restrict__ pre) {
    const int b = blockIdx.y, c0 = blockIdx.x * 32;
    __shared__ float xp_[256 * 32];        // [(i+2)*16 + (j+1)][cc]
    __shared__ float part[8][9][32];
    __shared__ float inv_norm[9][32];
    const int tid = threadIdx.x;
    const int cc = tid & 31, g = tid >> 5;

#pragma unroll
    for (int q = 0; q < 32; ++q) xp_[q * 256 + tid] = 0.0f;
    __syncthreads();

    for (int idx = tid; idx < (P * 32) / 4; idx += 256) {
        const int f = idx * 4;
        const int p = f >> 5, c = f & 31;
        const int i = p / HH, j = p % HH;
        *(float4*)&xp_[((i + 2) * 16 + (j + 1)) * 32 + c] =
            *(const float4*)&t[((size_t)b * P + p) * C + c0 + c];
    }
    __syncthreads();

    float s[9] = {};
    {
        int i = 0, j = g;
        for (int p = g; p < P; p += 8) {
            const int base = ((i + 2) * 16 + (j + 1)) * 32 + cc;
            const float xp = xp_[base];
            const float xp2 = xp * xp;
#pragma unroll
            for (int k = 0; k < 9; ++k) {
                const int off = ((k / 3) - 2) * 16 + (k % 3) - 1;  // const
                const float nb = xp_[base + off * 32];
                s[k] += xp2 * nb * nb;
            }
            j += 8;
            if (j >= HH) { j -= HH; ++i; }
        }
    }
#pragma unroll
    for (int k = 0; k < 9; ++k) part[g][k][cc] = s[k];
    __syncthreads();
    for (int k = g; k < 9; k += 8) {
        float t4 = 0.0f;
#pragma unroll
        for (int q = 0; q < 8; ++q) t4 += part[q][k][cc];
        inv_norm[k][cc] = 1.0f / fmaxf(sqrtf(t4), 1e-12f);
    }
    __syncthreads();

    float invn[9];
#pragma unroll
    for (int k = 0; k < 9; ++k) invn[k] = inv_norm[k][cc];

    {
        int i = 0, j = g;
        for (int p = g; p < P; p += 8) {
            const int base = ((i + 2) * 16 + (j + 1)) * 32 + cc;
            const float xp = xp_[base];
            float acc = 0.0f;
#pragma unroll
            for (int k = 0; k < 9; ++k) {
                const int off = ((k / 3) - 2) * 16 + (k % 3) - 1;
                const float v = xp * xp_[base + off * 32];
                const float u = fmaxf(v * invn[k], 1e-6f);
                acc += u * u * u;
            }
            pre[((size_t)b * P + p) * C + c0 + cc] =
                cbrtf(acc * (1.0f / 9.0f)) + xp;
            j += 8;
            if (j >= HH) { j -= HH; ++i; }
        }
    }
}

// ---------------------------------------------------------------------------
// K2: L2 normalize each (b,p) row over 768 channels; write f16 tokens.
// ---------------------------------------------------------------------------
__global__ __launch_bounds__(256) void k_rownorm(const float* __restrict__ in,
                                                 _Float16* __restrict__ out) {
    const int row = blockIdx.x;               // b*P + p
    const float* r = in + (size_t)row * C;
    const int tid = threadIdx.x;
    float vals[3];
    float s = 0.0f;
#pragma unroll
    for (int q = 0; q < 3; ++q) {
        vals[q] = r[tid + q * 256];
        s += vals[q] * vals[q];
    }
    __shared__ float partial[4];
    __shared__ float inv;
#pragma unroll
    for (int off = 32; off > 0; off >>= 1) s += __shfl_xor(s, off);
    if ((tid & 63) == 0) partial[tid >> 6] = s;
    __syncthreads();
    if (tid == 0)
        inv = 1.0f / fmaxf(sqrtf(partial[0] + partial[1] + partial[2] + partial[3]), 1e-12f);
    __syncthreads();
    _Float16* o = out + (size_t)row * C;
#pragma unroll
    for (int q = 0; q < 3; ++q) o[tid + q * 256] = (_Float16)(vals[q] * inv);
}

// ---------------------------------------------------------------------------
// K2b: weight transpose + f32->f16:  W (K x N) -> Wt (N x K)
// ---------------------------------------------------------------------------
__global__ __launch_bounds__(256) void k_wt(const float* __restrict__ W,
                                            _Float16* __restrict__ Wt) {
    __shared__ float t[32][33];
    const int k0 = blockIdx.x * 32, n0 = blockIdx.y * 32;
    const int r = threadIdx.x / 32, c = threadIdx.x % 32;
#pragma unroll
    for (int q = 0; q < 4; ++q)
        t[r + q * 8][c] = W[(size_t)(k0 + r + q * 8) * C + n0 + c];
    __syncthreads();
#pragma unroll
    for (int q = 0; q < 4; ++q)
        Wt[(size_t)(n0 + r + q * 8) * C + k0 + c] = (_Float16)t[c][r + q * 8];
}

// ---------------------------------------------------------------------------
// K3/K4: f16 MFMA GEMM, 2-phase double-buffered.
// Tile 64M x 128N, BK=32, 4 waves, grid 98x6 = 588 blocks.
// ---------------------------------------------------------------------------
template <bool GELU>
__global__ __launch_bounds__(256) void k_mfma_gemm(
    const _Float16* __restrict__ Tok,   // (M=6272, K=768)
    const _Float16* __restrict__ Wt,    // (N=768,  K=768)
    const float* __restrict__ bias,     // (N)
    void* __restrict__ Cout) {          // f16 (GELU) or f32
    __shared__ _Float16 lA[2][4][128][8];  // [buf][kb][n][k']
    __shared__ _Float16 lB[2][4][64][8];   // [buf][kb][m][k']
    const int tid = threadIdx.x;
    const int w = tid >> 6, l = tid & 63;
    const int l15 = l & 15, lk = l >> 4;
    const int m0 = blockIdx.x * 64, n0 = blockIdx.y * 128;
    const int wn = (w & 1) * 64, wm = (w >> 1) * 32;

    f32x4 acc[4][2] = {};   // [fa over n][fb over m]

    const _Float16* gA0 = Wt + (size_t)(n0 + l) * C + w * 8;
    const _Float16* gA1 = Wt + (size_t)(n0 + 64 + l) * C + w * 8;
    const _Float16* gB0 = Tok + (size_t)(m0 + l) * C + w * 8;

    GLOAD_LDS16(gA0, &lA[0][w][0][0]);
    GLOAD_LDS16(gA1, &lA[0][w][64][0]);
    GLOAD_LDS16(gB0, &lB[0][w][0][0]);
    __syncthreads();

    int cur = 0;
    for (int t = 0; t < 24; ++t) {
        if (t < 23) {                      // issue next tile FIRST
            const int kt = (t + 1) * 32;
            GLOAD_LDS16(gA0 + kt, &lA[cur ^ 1][w][0][0]);
            GLOAD_LDS16(gA1 + kt, &lA[cur ^ 1][w][64][0]);
            GLOAD_LDS16(gB0 + kt, &lB[cur ^ 1][w][0][0]);
        }
        half8 af[4], bf[2];
#pragma unroll
        for (int fa = 0; fa < 4; ++fa)
            af[fa] = *(const half8*)&lA[cur][lk][wn + fa * 16 + l15][0];
#pragma unroll
        for (int fb = 0; fb < 2; ++fb)
            bf[fb] = *(const half8*)&lB[cur][lk][wm + fb * 16 + l15][0];
#pragma unroll
        for (int fa = 0; fa < 4; ++fa)
#pragma unroll
            for (int fb = 0; fb < 2; ++fb)
                acc[fa][fb] = __builtin_amdgcn_mfma_f32_16x16x32_f16(
                    af[fa], bf[fb], acc[fa][fb], 0, 0, 0);
        __syncthreads();
        cur ^= 1;
    }

#pragma unroll
    for (int fa = 0; fa < 4; ++fa) {
        const int nb = n0 + wn + fa * 16 + lk * 4;
        const float4 bv = *(const float4*)&bias[nb];
#pragma unroll
        for (int fb = 0; fb < 2; ++fb) {
            const int m = m0 + wm + fb * 16 + l15;
            if (GELU) {
                half4 o;
#pragma unroll
                for (int r = 0; r < 4; ++r) {
                    float v = acc[fa][fb][r] + ((const float*)&bv)[r];
                    v = 0.5f * v * (1.0f + erff(v * 0.70710678118654752f));
                    o[r] = (_Float16)v;
                }
                *(half4*)&((_Float16*)Cout)[(size_t)m * C + nb] = o;
            } else {
                float4 o;
#pragma unroll
                for (int r = 0; r < 4; ++r)
                    ((float*)&o)[r] = acc[fa][fb][r] + ((const float*)&bv)[r];
                *(float4*)&((float*)Cout)[(size_t)m * C + nb] = o;
            }
        }
    }
}

// ---------------------------------------------------------------------------
// K5: GeM over tokens: g[b,c] = (mean_p clip(x,1e-6)^3)^(1/3)
// ---------------------------------------------------------------------------
__global__ __launch_bounds__(256) void k_gempool(const float* __restrict__ tk,
                                                 float* __restrict__ g) {
    const int b = blockIdx.x / 3;
    const int c = (blockIdx.x % 3) * 256 + threadIdx.x;
    float s = 0.0f;
#pragma unroll 4
    for (int p = 0; p < P; ++p) {
        const float v = fmaxf(tk[((size_t)b * P + p) * C + c], 1e-6f);
        s += v * v * v;
    }
    g[b * C + c] = cbrtf(s * (1.0f / (float)P));
}

// ---------------------------------------------------------------------------
// K6a: head GEMM stage 1 (split-K).  grid (NC/64, KSPLIT) = 64 x 24 = 1536
// blocks.  Block: 64 cols, 32 k-values, all 32 batches.  Thread = 1 col x
// 8 k x 32 batch accums; fixed-order 4-way combine via LDS; writes
// partial[ks][b][n] (12.6 MB).
// ---------------------------------------------------------------------------
__global__ __launch_bounds__(256) void k_head1(const float* __restrict__ g,
                                               const float* __restrict__ W,
                                               float* __restrict__ partial) {
    const int n0 = blockIdx.x * 64;
    const int k0 = blockIdx.y * 32;
    __shared__ float gs[32][32];          // [b][kk]
    __shared__ float part[4][32][64];     // [q][b][c]
    const int tid = threadIdx.x;

    for (int idx = tid; idx < 32 * 32; idx += 256)
        gs[idx >> 5][idx & 31] = g[(idx >> 5) * C + k0 + (idx & 31)];
    __syncthreads();

    const int c = tid & 63, q = tid >> 6;
    float acc[32] = {};
#pragma unroll
    for (int kk = 0; kk < 8; ++kk) {
        const int k = q * 8 + kk;
        const float wv = W[(size_t)(k0 + k) * NC + n0 + c];
#pragma unroll
        for (int b = 0; b < 32; ++b) acc[b] += gs[b][k] * wv;
    }
#pragma unroll
    for (int b = 0; b < 32; ++b) part[q][b][c] = acc[b];
    __syncthreads();

    for (int o = tid; o < 32 * 64; o += 256) {
        const int b = o >> 6, cc = o & 63;
        const float v = part[0][b][cc] + part[1][b][cc] +
                        part[2][b][cc] + part[3][b][cc];
        partial[((size_t)blockIdx.y * 32 + b) * NC + n0 + cc] = v;
    }
}

// ---------------------------------------------------------------------------
// K6b: head GEMM stage 2: fixed-order sum of KSPLIT partials + bias.
// grid (NC/256, B) = 16 x 32 = 512 blocks.
// ---------------------------------------------------------------------------
__global__ __launch_bounds__(256) void k_head2(const float* __restrict__ partial,
                                               const float* __restrict__ hb,
                                               float* __restrict__ out) {
    const int n = blockIdx.x * 256 + threadIdx.x;
    const int b = blockIdx.y;
    float s = hb[n];
#pragma unroll
    for (int ks = 0; ks < KSPLIT; ++ks)
        s += partial[((size_t)ks * 32 + b) * NC + n];
    out[(size_t)b * NC + n] = s;
}

// ---------------------------------------------------------------------------
// K7: L2-normalize each batch row of out (4096) in place.
// ---------------------------------------------------------------------------
__global__ __launch_bounds__(256) void k_outnorm(float* __restrict__ out) {
    const int b = blockIdx.x;
    float* r = out + (size_t)b * NC;
    const int tid = threadIdx.x;
    float v[16];
    float s = 0.0f;
#pragma unroll
    for (int q = 0; q < 16; ++q) {
        v[q] = r[tid + q * 256];
        s += v[q] * v[q];
    }
    __shared__ float partial[4];
    __shared__ float inv;
#pragma unroll
    for (int off = 32; off > 0; off >>= 1) s += __shfl_xor(s, off);
    if ((tid & 63) == 0) partial[tid >> 6] = s;
    __syncthreads();
    if (tid == 0)
        inv = 1.0f / fmaxf(sqrtf(partial[0] + partial[1] + partial[2] + partial[3]), 1e-12f);
    __syncthreads();
#pragma unroll
    for (int q = 0; q < 16; ++q) r[tid + q * 256] = v[q] * inv;
}

// ---------------------------------------------------------------------------
extern "C" void kernel_launch(void* const* d_in, const int* in_sizes, int n_in,
                              void* d_out, int out_size, void* d_ws, size_t ws_size,
                              hipStream_t stream) {
    const float* patch  = (const float*)d_in[0];
    const float* fc1_w  = (const float*)d_in[1];
    const float* fc1_b  = (const float*)d_in[2];
    const float* fc2_w  = (const float*)d_in[3];
    const float* fc2_b  = (const float*)d_in[4];
    const float* head_w = (const float*)d_in[5];
    const float* head_b = (const float*)d_in[6];
    float* out = (float*)d_out;

    const size_t big = (size_t)B * P * C;        // 4,816,896 elements
    float*    pre  = (float*)d_ws;               // [big] f32; later reused as tok2
    _Float16* tokN = (_Float16*)(pre + big);     // [big] f16
    _Float16* hdn  = tokN + big;                 // [big] f16
    _Float16* wt1  = hdn + big;                  // [768*768] f16
    _Float16* wt2  = wt1 + C * C;                // [768*768] f16
    float*    gbuf = (float*)(wt2 + C * C);      // [32*768] f32
    float*    hpart = gbuf + B * C;              // [KSPLIT*32*4096] f32
    float*    tok2 = pre;                        // reuse

    // K1: SSA + fusion + residual -> pre
    k_ssa<<<dim3(C / 32, B), dim3(256), 0, stream>>>(patch, pre);
    // weight transposes (independent)
    k_wt<<<dim3(C / 32, C / 32), dim3(256), 0, stream>>>(fc1_w, wt1);
    k_wt<<<dim3(C / 32, C / 32), dim3(256), 0, stream>>>(fc2_w, wt2);
    // K2: channel L2 norm -> tokN (f16)
    k_rownorm<<<dim3(B * P), dim3(256), 0, stream>>>(pre, tokN);
    // K3: fc1 + gelu -> hdn (f16)
    k_mfma_gemm<true><<<dim3((B * P) / 64, C / 128), dim3(256), 0, stream>>>(
        tokN, wt1, fc1_b, hdn);
    // K4: fc2 -> tok2 (f32)
    k_mfma_gemm<false><<<dim3((B * P) / 64, C / 128), dim3(256), 0, stream>>>(
        hdn, wt2, fc2_b, tok2);
    // K5: GeM over tokens -> gbuf
    k_gempool<<<dim3(B * 3), dim3(256), 0, stream>>>(tok2, gbuf);
    // K6: head GEMM, split-K two-stage -> out (pre-normalized)
    k_head1<<<dim3(NC / 64, KSPLIT), dim3(256), 0, stream>>>(gbuf, head_w, hpart);
    k_head2<<<dim3(NC / 256, B), dim3(256), 0, stream>>>(hpart, head_b, out);
    // K7: normalize rows of out
    k_outnorm<<<dim3(B), dim3(256), 0, stream>>>(out);
}